// Round 1
// 403.565 us; speedup vs baseline: 1.3981x; 1.3981x over previous
//
#include <hip/hip_runtime.h>
#include <hip/hip_bf16.h>

#define Bn 16
#define Nn 4096
#define Pn 1024
#define Sn 32
#define Cn 64
#define EPSn 1e-5f
#define ALPHAn 0.2f

// ---- fp32 weight table (fps scalar path) ----
#define W1O 0       // [68][64] k-order [feat64|xyz3|pad]
#define W2O 4352    // [64][64]
#define W3O 8448    // [64][128]
#define AO  16640   // two col-halves [132][64]; k-order [h3|xyz|pad]
#define B1O 33536
#define B2O 33600
#define B3O 33664
#define WSF 33792
__device__ __align__(16) float g_W[WSF];

// ---- FRAGMENT-MAJOR split-bf16 weights: g_Wf[frag][lane][8] u16 ----
#define F1F 0
#define F2F 24
#define F3F 40
#define F5F 72
#define NFRAG 152
#define WFU (NFRAG * 512)
__device__ __align__(16) unsigned short g_Wf[WFU];

// ---- row-major point store [b][n][68]; fps precompute; out1 staging ----
__device__ __align__(16) float g_pts[Bn * Nn * 68];
__device__ __align__(16) float g_fps[Bn * Pn * 132];   // [0..127]=ebias, [128..130]=new_xyz
__device__ __align__(16) float g_tmp[Bn * Pn * 128];

typedef __attribute__((ext_vector_type(8))) short short8;
typedef __attribute__((ext_vector_type(4))) float f32x4;

__device__ __forceinline__ void split2(float v, unsigned short& hu, unsigned short& lu) {
  __hip_bfloat16 h = __float2bfloat16(v);
  float hv = __bfloat162float(h);
  __hip_bfloat16 l = __float2bfloat16(v - hv);
  hu = *(unsigned short*)&h;
  lu = *(unsigned short*)&l;
}
__device__ __forceinline__ unsigned short bfh(float v) {
  __hip_bfloat16 h = __float2bfloat16(v);
  return *(unsigned short*)&h;
}
__device__ __forceinline__ float bf2f(unsigned short u) {
  __hip_bfloat16 h = *(__hip_bfloat16*)&u;
  return __bfloat162float(h);
}

// Merged prep: blocks [0,1024) transpose points->g_pts; rest fold weights.
__global__ __launch_bounds__(256) void prep_kernel(
    const float* __restrict__ xyz, const float* __restrict__ points,
    const float* __restrict__ w1, const float* __restrict__ b1,
    const float* __restrict__ g1, const float* __restrict__ bt1,
    const float* __restrict__ m1, const float* __restrict__ v1,
    const float* __restrict__ w2, const float* __restrict__ b2,
    const float* __restrict__ g2, const float* __restrict__ bt2,
    const float* __restrict__ m2, const float* __restrict__ v2,
    const float* __restrict__ w3, const float* __restrict__ b3,
    const float* __restrict__ g3, const float* __restrict__ bt3,
    const float* __restrict__ m3, const float* __restrict__ v3,
    const float* __restrict__ a)
{
  if (blockIdx.x < 1024) {   // transpose tile
    __shared__ float T[68 * 65];
    const int t = threadIdx.x;
    const int b = blockIdx.x >> 6, n0 = (blockIdx.x & 63) << 6;
    const int nn = t & 63, cgrp = t >> 6;
    #pragma unroll
    for (int k = 0; k < 16; ++k) {
      const int c = cgrp * 16 + k;
      T[c * 65 + nn] = points[(b * Cn + c) * Nn + n0 + nn];
    }
    if (cgrp == 0) {
      #pragma unroll
      for (int d = 0; d < 3; ++d)
        T[(64 + d) * 65 + nn] = xyz[(b * 3 + d) * Nn + n0 + nn];
      T[67 * 65 + nn] = 0.f;
    }
    __syncthreads();
    // coalesced float4 writes: lane covers (row, part)
    const int row = t >> 2, part = t & 3;
    float* dst = g_pts + (((long)b << 12) + n0 + row) * 68 + part * 16;
    #pragma unroll
    for (int j = 0; j < 4; ++j) {
      const int o = part * 16 + j * 4;
      float4 v = { T[(o + 0) * 65 + row], T[(o + 1) * 65 + row],
                   T[(o + 2) * 65 + row], T[(o + 3) * 65 + row] };
      *(float4*)(dst + j * 4) = v;
    }
    if (part == 3) {
      float4 v = { T[64 * 65 + row], T[65 * 65 + row],
                   T[66 * 65 + row], T[67 * 65 + row] };
      *(float4*)(dst + 16) = v;
    }
    return;
  }
  const int idx = (blockIdx.x - 1024) * blockDim.x + threadIdx.x;
  if (idx < WSF) {
    float val;
    if (idx < W2O) {
      const int k = idx >> 6, o = idx & 63;
      const float sc = g1[o] * rsqrtf(v1[o] + EPSn);
      val = (k < 64) ? w1[o * 67 + 3 + k] * sc
          : (k < 67) ? w1[o * 67 + (k - 64)] * sc : 0.f;
    } else if (idx < W3O) {
      const int r = idx - W2O, k = r >> 6, o = r & 63;
      val = w2[o * 64 + k] * (g2[o] * rsqrtf(v2[o] + EPSn));
    } else if (idx < AO) {
      const int r = idx - W3O, k = r >> 7, o = r & 127;
      val = w3[o * 64 + k] * (g3[o] * rsqrtf(v3[o] + EPSn));
    } else if (idx < B1O) {
      int r = idx - AO;
      const int half = r / 8448; r -= half * 8448;
      const int k = r >> 6, o = half * 64 + (r & 63);
      val = (k < 128) ? a[(3 + k) * 128 + o]
          : (k < 131) ? a[(k - 128) * 128 + o] : 0.f;
    } else if (idx < B2O) {
      const int o = idx - B1O;
      val = (b1[o] - m1[o]) * (g1[o] * rsqrtf(v1[o] + EPSn)) + bt1[o];
    } else if (idx < B3O) {
      const int o = idx - B2O;
      val = (b2[o] - m2[o]) * (g2[o] * rsqrtf(v2[o] + EPSn)) + bt2[o];
    } else {
      const int o = idx - B3O;
      val = (b3[o] - m3[o]) * (g3[o] * rsqrtf(v3[o] + EPSn)) + bt3[o];
    }
    g_W[idx] = val;
  } else if (idx < WSF + WFU) {
    const int i = idx - WSF;
    const int frag = i >> 9, r = i & 511;
    const int lane = r >> 3, j = r & 7;
    const int quad = lane >> 4, nn = lane & 15;
    int plane, n, k;
    float w;
    if (frag < F2F) {                 // phase1: W1, C=2
      const int f = frag;
      plane = f & 1;
      const int c = (f >> 1) & 1, kcch = f >> 2, kc = kcch % 3, ch = kcch / 3;
      n = ch * 32 + c * 16 + nn; k = kc * 32 + quad * 8 + j;
      const float s = g1[n] * rsqrtf(v1[n] + EPSn);
      w = (k < 64) ? w1[n * 67 + 3 + k] * s
        : (k < 67) ? w1[n * 67 + (k - 64)] * s : 0.f;
    } else if (frag < F3F) {          // phase2: W2, C=2
      const int f = frag - F2F;
      plane = f & 1;
      const int c = (f >> 1) & 1, kc = (f >> 2) & 1, ch = f >> 3;
      n = ch * 32 + c * 16 + nn; k = kc * 32 + quad * 8 + j;
      w = w2[n * 64 + k] * (g2[n] * rsqrtf(v2[n] + EPSn));
    } else if (frag < F5F) {          // phase3: W3, C=4
      const int f = frag - F3F;
      plane = f & 1;
      const int c = (f >> 1) & 3, kc = (f >> 3) & 1, ch = f >> 4;
      n = ch * 64 + c * 16 + nn; k = kc * 32 + quad * 8 + j;
      w = w3[n * 64 + k] * (g3[n] * rsqrtf(v3[n] + EPSn));
    } else {                          // phase5: A, C=4, KC=5
      const int f = frag - F5F;
      plane = f & 1;
      const int c = (f >> 1) & 3, kcch = f >> 3, kc = kcch % 5, ch = kcch / 5;
      n = ch * 64 + c * 16 + nn; k = kc * 32 + quad * 8 + j;
      w = (k < 128) ? a[(3 + k) * 128 + n]
        : (k < 131) ? a[(k - 128) * 128 + n] : 0.f;
    }
    unsigned short hu, lu; split2(w, hu, lu);
    g_Wf[i] = plane ? lu : hu;
  }
}

// fps-point MLP + ebias, hoisted out of the fused kernel. One block per (b,p).
// fp32 scalar path -> numerics identical to previous in-fused version.
__global__ __launch_bounds__(128) void fps_kernel(
    const int* __restrict__ fps_idx, float* __restrict__ out)
{
  __shared__ float FS[200];   // [0..2]=xyz, [4..67]=feat/h2, [68..195]=h1/h3
  const int t = threadIdx.x;
  const int g = blockIdx.x, b = g >> 10, p = g & 1023;
  {
    const int fi = fps_idx[g];
    const float* frow = g_pts + (((long)b << 12) + fi) * 68;
    if (t < 64) {
      FS[4 + t] = frow[t];
    } else if (t < 67) {
      const int d = t - 64;
      const float v = frow[t];
      FS[d] = v;
      out[(b * 3 + d) * Pn + p] = v;
      g_fps[(long)g * 132 + 128 + d] = v;
    }
  }
  __syncthreads();
  { // L1 -> FS[68+o], o<64
    const int o = t >> 1, kh = t & 1;
    float a2 = 0.f;
    if (kh == 0) {
      #pragma unroll 2
      for (int k = 0; k < 34; ++k) a2 = fmaf(FS[4 + k], g_W[W1O + k * 64 + o], a2);
    } else {
      #pragma unroll 2
      for (int k = 34; k < 64; ++k) a2 = fmaf(FS[4 + k], g_W[W1O + k * 64 + o], a2);
      #pragma unroll
      for (int d = 0; d < 3; ++d) a2 = fmaf(FS[d], g_W[W1O + (64 + d) * 64 + o], a2);
    }
    a2 += __shfl_xor(a2, 1);
    if (kh == 0) FS[68 + o] = fmaxf(a2 + g_W[B1O + o], 0.f);
  }
  __syncthreads();
  { // L2 -> FS[4+o], o<64
    const int o = t >> 1, kh = t & 1;
    float a2 = 0.f;
    #pragma unroll 2
    for (int k = kh * 32; k < kh * 32 + 32; ++k)
      a2 = fmaf(FS[68 + k], g_W[W2O + k * 64 + o], a2);
    a2 += __shfl_xor(a2, 1);
    if (kh == 0) FS[4 + o] = fmaxf(a2 + g_W[B2O + o], 0.f);
  }
  __syncthreads();
  { // L3 -> FS[68+o], o<128
    const int o = t;
    float a2 = 0.f;
    #pragma unroll 4
    for (int k = 0; k < 64; ++k)
      a2 = fmaf(FS[4 + k], g_W[W3O + k * 128 + o], a2);
    FS[68 + o] = fmaxf(a2 + g_W[B3O + o], 0.f);
  }
  __syncthreads();
  { // ebias -> g_fps[g][o]
    const int o = t;
    const float* ap = g_W + AO + (o >> 6) * 8448 + (o & 63);
    float a2 = 0.f;
    #pragma unroll 4
    for (int k = 0; k < 128; ++k) a2 = fmaf(FS[68 + k], ap[k * 64], a2);
    #pragma unroll
    for (int d = 0; d < 3; ++d) a2 = fmaf(FS[d], ap[(128 + d) * 64], a2);
    g_fps[(long)g * 132 + o] = a2;
  }
}

// Epilogue: g_tmp[b][p][128] -> out1[b][c][p]
__global__ __launch_bounds__(256) void transpose_out(float* __restrict__ out)
{
  __shared__ float T[64 * 129];
  const int t = threadIdx.x;
  const int b = blockIdx.x >> 4, p0 = (blockIdx.x & 15) << 6;
  const int c = t & 127, ph = t >> 7;
  #pragma unroll
  for (int pp = 0; pp < 32; ++pp) {
    const int pi = ph * 32 + pp;
    T[pi * 129 + c] = g_tmp[(((long)b << 10) + p0 + pi) * 128 + c];
  }
  __syncthreads();
  const int pn = t & 63, cg = t >> 6;
  #pragma unroll
  for (int k = 0; k < 32; ++k) {
    const int cc = cg * 32 + k;
    out[Bn * 3 * Pn + ((b << 7) + cc) * Pn + p0 + pn] = T[pn * 129 + cc];
  }
}

// ---- fused kernel LDS (bytes). Strides chosen so ds_read_b128 A-loads are
// perfectly balanced (bank step = stride/2 mod 32 = 12 -> 8 lanes / 4-bank
// group = the 1KB/wave minimum, zero extra conflict). Total 15888 B ->
// 8 blocks/CU (wave-slot cap) with launch_bounds(256,8).
#define XAs 88    // u16 stride, data cols 0..79 (64 feat + 3 xyz + 13 zero)
#define XHs 152   // u16 stride, data cols 0..143 (128 h + 3 rxyz + 13 zero)
#define OXA 0            // 32*88*2  = 5632
#define OXH 5632         // 32*152*2 = 9728 -> 15360
#define OFS 15360        // 128 f32  = 512  -> 15872
#define OZS 15872        // 16 B zero stub  -> 15888
#define LDSB 15888
// softmax combine buffers alias dead XA space (XA last read in phase 3):
#define OSM   0          // [2][128] f32 per-wave max
#define ODEN  1024       // [2][128] f32 partial denom
#define OPOOL 2048       // [2][128] f32 partial pooled

#define MFMA_BF16 __builtin_amdgcn_mfma_f32_16x16x32_bf16

__global__ __launch_bounds__(256, 8) void fused_kernel(
    const int* __restrict__ group_idx)
{
  __shared__ __align__(16) unsigned char LB[LDSB];
  unsigned short* XAh = (unsigned short*)(LB + OXA);
  unsigned short* XHh = (unsigned short*)(LB + OXH);
  float*          FS  = (float*)(LB + OFS);
  unsigned short* ZS  = (unsigned short*)(LB + OZS);
  float*          SM  = (float*)(LB + OSM);
  float*          DEN = (float*)(LB + ODEN);
  float*          POOL= (float*)(LB + OPOOL);

  const int t = threadIdx.x, lane = t & 63, wave = t >> 6;
  const int quad = lane >> 4, nn = lane & 15;
  const int mt = wave >> 1, ch = wave & 1;
  const int m0 = mt * 16;
  const int g = blockIdx.x;
  const int b = g >> 10;

  // ---- S0: stage ebias; zero stub ----
  if (t < 128) FS[t] = g_fps[(long)g * 132 + t];
  if (t < 4) ((float*)ZS)[t] = 0.f;

  // ---- S1: gather group rows -> XAh (packed b128 stores); rxyz; pads ----
  {
    const int s0 = t >> 3, cg = t & 7;
    const int gi = group_idx[g * Sn + s0];
    const float* prow = g_pts + (((long)b << 12) + gi) * 68;
    const int c0 = cg * 8;
    const float4 va = *(const float4*)(prow + c0);
    const float4 vb = *(const float4*)(prow + c0 + 4);
    short8 hv;
    hv[0] = (short)bfh(va.x); hv[1] = (short)bfh(va.y);
    hv[2] = (short)bfh(va.z); hv[3] = (short)bfh(va.w);
    hv[4] = (short)bfh(vb.x); hv[5] = (short)bfh(vb.y);
    hv[6] = (short)bfh(vb.z); hv[7] = (short)bfh(vb.w);
    *(short8*)(XAh + s0 * XAs + c0) = hv;
    if (cg == 0) {
      #pragma unroll
      for (int d = 0; d < 3; ++d) {
        const float r = prow[64 + d] - g_fps[(long)g * 132 + 128 + d];
        const unsigned short hu = bfh(r);
        XAh[s0 * XAs + 64 + d] = hu;
        XHh[s0 * XHs + 128 + d] = hu;
      }
    } else if (cg == 1) {
      #pragma unroll
      for (int j = 0; j < 13; ++j) XAh[s0 * XAs + 67 + j] = 0;
    } else if (cg == 2) {
      #pragma unroll
      for (int j = 0; j < 13; ++j) XHh[s0 * XHs + 131 + j] = 0;
    }
  }
  __syncthreads();

  f32x4 C[4];

  // ===== Phase 1: X(K96) @ W1f -> h1 (XHh cols 0..63) =====
  C[0] = (f32x4){0.f,0.f,0.f,0.f}; C[1] = (f32x4){0.f,0.f,0.f,0.f};
  #pragma unroll
  for (int kc = 0; kc < 3; ++kc) {
    const int ka = kc * 32 + quad * 8;
    const short8 Ah = (ka < 80) ? *(const short8*)(XAh + (m0 + nn) * XAs + ka)
                                : *(const short8*)ZS;
    #pragma unroll
    for (int c = 0; c < 2; ++c) {
      const unsigned short* pf = g_Wf + (((ch * 3 + kc) * 2 + c) * 2) * 512 + lane * 8;
      C[c] = MFMA_BF16(Ah, *(const short8*)pf, C[c], 0, 0, 0);
      C[c] = MFMA_BF16(Ah, *(const short8*)(pf + 512), C[c], 0, 0, 0);
    }
  }
  #pragma unroll
  for (int c = 0; c < 2; ++c) {
    const int col = ch * 32 + c * 16 + nn;
    #pragma unroll
    for (int r = 0; r < 4; ++r)
      XHh[(m0 + quad * 4 + r) * XHs + col] = bfh(fmaxf(C[c][r] + g_W[B1O + col], 0.f));
  }
  __syncthreads();

  // ===== Phase 2: h1(K64, XHh) @ W2f -> h2 (XAh cols 0..63) =====
  C[0] = (f32x4){0.f,0.f,0.f,0.f}; C[1] = (f32x4){0.f,0.f,0.f,0.f};
  #pragma unroll
  for (int kc = 0; kc < 2; ++kc) {
    const int ka = kc * 32 + quad * 8;
    const short8 Ah = *(const short8*)(XHh + (m0 + nn) * XHs + ka);
    #pragma unroll
    for (int c = 0; c < 2; ++c) {
      const unsigned short* pf = g_Wf + (F2F + ((ch * 2 + kc) * 2 + c) * 2) * 512 + lane * 8;
      C[c] = MFMA_BF16(Ah, *(const short8*)pf, C[c], 0, 0, 0);
      C[c] = MFMA_BF16(Ah, *(const short8*)(pf + 512), C[c], 0, 0, 0);
    }
  }
  #pragma unroll
  for (int c = 0; c < 2; ++c) {
    const int col = ch * 32 + c * 16 + nn;
    #pragma unroll
    for (int r = 0; r < 4; ++r)
      XAh[(m0 + quad * 4 + r) * XAs + col] = bfh(fmaxf(C[c][r] + g_W[B2O + col], 0.f));
  }
  __syncthreads();

  // ===== Phase 3: h2(K64, XAh) @ W3f -> h3 (XHh cols 0..127) =====
  #pragma unroll
  for (int i = 0; i < 4; ++i) C[i] = (f32x4){0.f,0.f,0.f,0.f};
  #pragma unroll
  for (int kc = 0; kc < 2; ++kc) {
    const int ka = kc * 32 + quad * 8;
    const short8 Ah = *(const short8*)(XAh + (m0 + nn) * XAs + ka);
    #pragma unroll
    for (int c = 0; c < 4; ++c) {
      const unsigned short* pf = g_Wf + (F3F + ((ch * 2 + kc) * 4 + c) * 2) * 512 + lane * 8;
      C[c] = MFMA_BF16(Ah, *(const short8*)pf, C[c], 0, 0, 0);
      C[c] = MFMA_BF16(Ah, *(const short8*)(pf + 512), C[c], 0, 0, 0);
    }
  }
  #pragma unroll
  for (int c = 0; c < 4; ++c) {
    const int col = ch * 64 + c * 16 + nn;
    #pragma unroll
    for (int r = 0; r < 4; ++r)
      XHh[(m0 + quad * 4 + r) * XHs + col] = bfh(fmaxf(C[c][r] + g_W[B3O + col], 0.f));
  }
  __syncthreads();

  // ===== Phase 5: [h3|rxyz](K160, XHh) @ Af -> scores (in registers) =====
  #pragma unroll
  for (int i = 0; i < 4; ++i) C[i] = (f32x4){0.f,0.f,0.f,0.f};
  #pragma unroll
  for (int kc = 0; kc < 5; ++kc) {
    const int ka = kc * 32 + quad * 8;
    const short8 Ah = (ka < 144) ? *(const short8*)(XHh + (m0 + nn) * XHs + ka)
                                 : *(const short8*)ZS;
    #pragma unroll
    for (int c = 0; c < 4; ++c) {
      const unsigned short* pf = g_Wf + (F5F + ((ch * 5 + kc) * 4 + c) * 2) * 512 + lane * 8;
      C[c] = MFMA_BF16(Ah, *(const short8*)pf, C[c], 0, 0, 0);
      C[c] = MFMA_BF16(Ah, *(const short8*)(pf + 512), C[c], 0, 0, 0);
    }
  }

  // ---- leaky scores in place + per-wave (16-row) max via cross-quad shfl ----
  #pragma unroll
  for (int c = 0; c < 4; ++c) {
    const int col = ch * 64 + c * 16 + nn;
    const float eb = FS[col];
    float m_ = -3.4e38f;
    #pragma unroll
    for (int r = 0; r < 4; ++r) {
      float e = eb - C[c][r];
      e = (e > 0.f) ? e : ALPHAn * e;
      C[c][r] = e;
      m_ = fmaxf(m_, e);
    }
    m_ = fmaxf(m_, __shfl_xor(m_, 16));
    m_ = fmaxf(m_, __shfl_xor(m_, 32));
    if (quad == 0) SM[mt * 128 + col] = m_;
  }
  __syncthreads();

  // ---- exp / denom / pooled partials; cross-quad reduce; cross-wave combine ----
  #pragma unroll
  for (int c = 0; c < 4; ++c) {
    const int col = ch * 64 + c * 16 + nn;
    const float m = fmaxf(SM[col], SM[128 + col]);
    float den = 0.f, pool = 0.f;
    #pragma unroll
    for (int r = 0; r < 4; ++r) {
      const float w = __expf(C[c][r] - m);
      den += w;
      pool = fmaf(w, bf2f(XHh[(m0 + quad * 4 + r) * XHs + col]), pool);
    }
    den  += __shfl_xor(den, 16);  den  += __shfl_xor(den, 32);
    pool += __shfl_xor(pool, 16); pool += __shfl_xor(pool, 32);
    if (quad == 0) { DEN[mt * 128 + col] = den; POOL[mt * 128 + col] = pool; }
  }
  __syncthreads();

  if (t < 128)
    g_tmp[(long)g * 128 + t] =
        (POOL[t] + POOL[128 + t]) / (DEN[t] + DEN[128 + t]);
}

extern "C" void kernel_launch(void* const* d_in, const int* in_sizes, int n_in,
                              void* d_out, int out_size, void* d_ws, size_t ws_size,
                              hipStream_t stream) {
  const float* xyz       = (const float*)d_in[0];
  const float* points    = (const float*)d_in[1];
  const int*   fps_idx   = (const int*)d_in[2];
  const int*   group_idx = (const int*)d_in[3];

  const int prep_blocks = 1024 + (WSF + WFU + 255) / 256;
  prep_kernel<<<prep_blocks, 256, 0, stream>>>(
      xyz, points,
      (const float*)d_in[4],  (const float*)d_in[5],
      (const float*)d_in[6],  (const float*)d_in[7],
      (const float*)d_in[8],  (const float*)d_in[9],
      (const float*)d_in[10], (const float*)d_in[11],
      (const float*)d_in[12], (const float*)d_in[13],
      (const float*)d_in[14], (const float*)d_in[15],
      (const float*)d_in[16], (const float*)d_in[17],
      (const float*)d_in[18], (const float*)d_in[19],
      (const float*)d_in[20], (const float*)d_in[21],
      (const float*)d_in[22]);

  fps_kernel<<<Bn * Pn, 128, 0, stream>>>(fps_idx, (float*)d_out);

  fused_kernel<<<Bn * Pn, 256, 0, stream>>>(group_idx);

  transpose_out<<<Bn * 16, 256, 0, stream>>>((float*)d_out);
}

// Round 2
// 238.838 us; speedup vs baseline: 2.3624x; 1.6897x over previous
//
#include <hip/hip_runtime.h>
#include <hip/hip_bf16.h>

#define Bn 16
#define Nn 4096
#define Pn 1024
#define Sn 32
#define Cn 64
#define EPSn 1e-5f
#define ALPHAn 0.2f

// ---- fp32 weight table (kept for bias rows + prep) ----
#define W1O 0       // [68][64] k-order [feat64|xyz3|pad]
#define W2O 4352    // [64][64]
#define W3O 8448    // [64][128]
#define AO  16640   // two col-halves [132][64]; k-order [h3|xyz|pad]
#define B1O 33536
#define B2O 33600
#define B3O 33664
#define WSF 33792
__device__ __align__(16) float g_W[WSF];

// ---- FRAGMENT-MAJOR split-bf16 weights: g_Wf[frag][lane][8] u16 ----
#define F1F 0
#define F2F 24
#define F3F 40
#define F5F 72
#define NFRAG 152
#define WFU (NFRAG * 512)
__device__ __align__(16) unsigned short g_Wf[WFU];

// ---- row-major point store [b][n][68]; fps precompute; out1 staging ----
__device__ __align__(16) float g_pts[Bn * Nn * 68];
__device__ __align__(16) float g_fps[Bn * Pn * 132];   // [0..127]=ebias, [128..130]=new_xyz
__device__ __align__(16) float g_tmp[Bn * Pn * 128];

typedef __attribute__((ext_vector_type(8))) short short8;
typedef __attribute__((ext_vector_type(4))) float f32x4;

__device__ __forceinline__ void split2(float v, unsigned short& hu, unsigned short& lu) {
  __hip_bfloat16 h = __float2bfloat16(v);
  float hv = __bfloat162float(h);
  __hip_bfloat16 l = __float2bfloat16(v - hv);
  hu = *(unsigned short*)&h;
  lu = *(unsigned short*)&l;
}
__device__ __forceinline__ unsigned short bfh(float v) {
  __hip_bfloat16 h = __float2bfloat16(v);
  return *(unsigned short*)&h;
}
__device__ __forceinline__ float bf2f(unsigned short u) {
  __hip_bfloat16 h = *(__hip_bfloat16*)&u;
  return __bfloat162float(h);
}

// Merged prep: blocks [0,1024) transpose points->g_pts; rest fold weights.
__global__ __launch_bounds__(256) void prep_kernel(
    const float* __restrict__ xyz, const float* __restrict__ points,
    const float* __restrict__ w1, const float* __restrict__ b1,
    const float* __restrict__ g1, const float* __restrict__ bt1,
    const float* __restrict__ m1, const float* __restrict__ v1,
    const float* __restrict__ w2, const float* __restrict__ b2,
    const float* __restrict__ g2, const float* __restrict__ bt2,
    const float* __restrict__ m2, const float* __restrict__ v2,
    const float* __restrict__ w3, const float* __restrict__ b3,
    const float* __restrict__ g3, const float* __restrict__ bt3,
    const float* __restrict__ m3, const float* __restrict__ v3,
    const float* __restrict__ a)
{
  if (blockIdx.x < 1024) {   // transpose tile
    __shared__ float T[68 * 65];
    const int t = threadIdx.x;
    const int b = blockIdx.x >> 6, n0 = (blockIdx.x & 63) << 6;
    const int nn = t & 63, cgrp = t >> 6;
    #pragma unroll
    for (int k = 0; k < 16; ++k) {
      const int c = cgrp * 16 + k;
      T[c * 65 + nn] = points[(b * Cn + c) * Nn + n0 + nn];
    }
    if (cgrp == 0) {
      #pragma unroll
      for (int d = 0; d < 3; ++d)
        T[(64 + d) * 65 + nn] = xyz[(b * 3 + d) * Nn + n0 + nn];
      T[67 * 65 + nn] = 0.f;
    }
    __syncthreads();
    const int row = t >> 2, part = t & 3;
    float* dst = g_pts + (((long)b << 12) + n0 + row) * 68 + part * 16;
    #pragma unroll
    for (int j = 0; j < 4; ++j) {
      const int o = part * 16 + j * 4;
      float4 v = { T[(o + 0) * 65 + row], T[(o + 1) * 65 + row],
                   T[(o + 2) * 65 + row], T[(o + 3) * 65 + row] };
      *(float4*)(dst + j * 4) = v;
    }
    if (part == 3) {
      float4 v = { T[64 * 65 + row], T[65 * 65 + row],
                   T[66 * 65 + row], T[67 * 65 + row] };
      *(float4*)(dst + 16) = v;
    }
    return;
  }
  const int idx = (blockIdx.x - 1024) * blockDim.x + threadIdx.x;
  if (idx < WSF) {
    float val;
    if (idx < W2O) {
      const int k = idx >> 6, o = idx & 63;
      const float sc = g1[o] * rsqrtf(v1[o] + EPSn);
      val = (k < 64) ? w1[o * 67 + 3 + k] * sc
          : (k < 67) ? w1[o * 67 + (k - 64)] * sc : 0.f;
    } else if (idx < W3O) {
      const int r = idx - W2O, k = r >> 6, o = r & 63;
      val = w2[o * 64 + k] * (g2[o] * rsqrtf(v2[o] + EPSn));
    } else if (idx < AO) {
      const int r = idx - W3O, k = r >> 7, o = r & 127;
      val = w3[o * 64 + k] * (g3[o] * rsqrtf(v3[o] + EPSn));
    } else if (idx < B1O) {
      int r = idx - AO;
      const int half = r / 8448; r -= half * 8448;
      const int k = r >> 6, o = half * 64 + (r & 63);
      val = (k < 128) ? a[(3 + k) * 128 + o]
          : (k < 131) ? a[(k - 128) * 128 + o] : 0.f;
    } else if (idx < B2O) {
      const int o = idx - B1O;
      val = (b1[o] - m1[o]) * (g1[o] * rsqrtf(v1[o] + EPSn)) + bt1[o];
    } else if (idx < B3O) {
      const int o = idx - B2O;
      val = (b2[o] - m2[o]) * (g2[o] * rsqrtf(v2[o] + EPSn)) + bt2[o];
    } else {
      const int o = idx - B3O;
      val = (b3[o] - m3[o]) * (g3[o] * rsqrtf(v3[o] + EPSn)) + bt3[o];
    }
    g_W[idx] = val;
  } else if (idx < WSF + WFU) {
    const int i = idx - WSF;
    const int frag = i >> 9, r = i & 511;
    const int lane = r >> 3, j = r & 7;
    const int quad = lane >> 4, nn = lane & 15;
    int plane, n, k;
    float w;
    if (frag < F2F) {                 // phase1: W1, C=2
      const int f = frag;
      plane = f & 1;
      const int c = (f >> 1) & 1, kcch = f >> 2, kc = kcch % 3, ch = kcch / 3;
      n = ch * 32 + c * 16 + nn; k = kc * 32 + quad * 8 + j;
      const float s = g1[n] * rsqrtf(v1[n] + EPSn);
      w = (k < 64) ? w1[n * 67 + 3 + k] * s
        : (k < 67) ? w1[n * 67 + (k - 64)] * s : 0.f;
    } else if (frag < F3F) {          // phase2: W2, C=2
      const int f = frag - F2F;
      plane = f & 1;
      const int c = (f >> 1) & 1, kc = (f >> 2) & 1, ch = f >> 3;
      n = ch * 32 + c * 16 + nn; k = kc * 32 + quad * 8 + j;
      w = w2[n * 64 + k] * (g2[n] * rsqrtf(v2[n] + EPSn));
    } else if (frag < F5F) {          // phase3: W3, C=4
      const int f = frag - F3F;
      plane = f & 1;
      const int c = (f >> 1) & 3, kc = (f >> 3) & 1, ch = f >> 4;
      n = ch * 64 + c * 16 + nn; k = kc * 32 + quad * 8 + j;
      w = w3[n * 64 + k] * (g3[n] * rsqrtf(v3[n] + EPSn));
    } else {                          // phase5: A, C=4, KC=5
      const int f = frag - F5F;
      plane = f & 1;
      const int c = (f >> 1) & 3, kcch = f >> 3, kc = kcch % 5, ch = kcch / 5;
      n = ch * 64 + c * 16 + nn; k = kc * 32 + quad * 8 + j;
      w = (k < 128) ? a[(3 + k) * 128 + n]
        : (k < 131) ? a[(k - 128) * 128 + n] : 0.f;
    }
    unsigned short hu, lu; split2(w, hu, lu);
    g_Wf[i] = plane ? lu : hu;
  }
}

// ---- shared LDS strides ----
#define XAs 88    // u16 stride (bank step 12 mod 32 -> balanced b128 reads)
#define XHs 152

// fps path as MFMA: 32 fps points per block, 512 blocks. Activations are
// split-bf16 (hi+lo) with 3-term products AhWh+AhWl+AlWh ~= fp32 precision,
// so ebias accuracy matches the old fp32 scalar path.
__global__ __launch_bounds__(256) void fps_kernel(
    const int* __restrict__ fps_idx, float* __restrict__ out)
{
  // XAh 0..5632, XAl ..11264, XHh ..20992, XHl ..30720, ZS ..30736
  __shared__ __align__(16) unsigned char LB[30736];
  unsigned short* XAh = (unsigned short*)(LB + 0);
  unsigned short* XAl = (unsigned short*)(LB + 5632);
  unsigned short* XHh = (unsigned short*)(LB + 11264);
  unsigned short* XHl = (unsigned short*)(LB + 20992);
  unsigned short* ZS  = (unsigned short*)(LB + 30720);

  const int t = threadIdx.x, lane = t & 63, w = t >> 6;
  const int quad = lane >> 4, nn = lane & 15;
  const int ch = w >> 1, cl = w & 1;
  const int blk = ((blockIdx.x & 7) << 6) | (blockIdx.x >> 3);  // XCD swizzle (512%8==0)
  const int g0 = blk * 32;

  if (t < 4) ((float*)ZS)[t] = 0.f;

  // gather 32 fps rows, split hi/lo
  {
    const int s0 = t >> 3, cg = t & 7;
    const int gp = g0 + s0, b = gp >> 10, p = gp & 1023;
    const int fi = fps_idx[gp];
    const float* frow = g_pts + (((long)b << 12) + fi) * 68;
    const int c0 = cg * 8;
    const float4 va = *(const float4*)(frow + c0);
    const float4 vb = *(const float4*)(frow + c0 + 4);
    short8 hv, lv;
    unsigned short hu, lu;
    split2(va.x, hu, lu); hv[0] = (short)hu; lv[0] = (short)lu;
    split2(va.y, hu, lu); hv[1] = (short)hu; lv[1] = (short)lu;
    split2(va.z, hu, lu); hv[2] = (short)hu; lv[2] = (short)lu;
    split2(va.w, hu, lu); hv[3] = (short)hu; lv[3] = (short)lu;
    split2(vb.x, hu, lu); hv[4] = (short)hu; lv[4] = (short)lu;
    split2(vb.y, hu, lu); hv[5] = (short)hu; lv[5] = (short)lu;
    split2(vb.z, hu, lu); hv[6] = (short)hu; lv[6] = (short)lu;
    split2(vb.w, hu, lu); hv[7] = (short)hu; lv[7] = (short)lu;
    *(short8*)(XAh + s0 * XAs + c0) = hv;
    *(short8*)(XAl + s0 * XAs + c0) = lv;
    if (cg == 0) {
      #pragma unroll
      for (int d = 0; d < 3; ++d) {
        const float v = frow[64 + d];
        unsigned short h2, l2; split2(v, h2, l2);
        XAh[s0 * XAs + 64 + d] = h2; XAl[s0 * XAs + 64 + d] = l2;
        XHh[s0 * XHs + 128 + d] = h2; XHl[s0 * XHs + 128 + d] = l2;
        out[(b * 3 + d) * Pn + p] = v;
        g_fps[(long)gp * 132 + 128 + d] = v;
      }
    } else if (cg == 1) {
      #pragma unroll
      for (int j = 0; j < 13; ++j) { XAh[s0 * XAs + 67 + j] = 0; XAl[s0 * XAs + 67 + j] = 0; }
    } else if (cg == 2) {
      #pragma unroll
      for (int j = 0; j < 13; ++j) { XHh[s0 * XHs + 131 + j] = 0; XHl[s0 * XHs + 131 + j] = 0; }
    }
  }
  __syncthreads();

#define MFMA_BF16 __builtin_amdgcn_mfma_f32_16x16x32_bf16
#define TERM3(Ci, Ahh, All, Bh, Bl) \
    Ci = MFMA_BF16(Ahh, Bh, Ci, 0, 0, 0); \
    Ci = MFMA_BF16(Ahh, Bl, Ci, 0, 0, 0); \
    Ci = MFMA_BF16(All, Bh, Ci, 0, 0, 0);

  f32x4 C[4];
  const int col1 = w * 16 + nn;

  // Phase 1: X(K96) @ W1 -> h1
  C[0] = (f32x4){0.f,0.f,0.f,0.f}; C[1] = C[0];
  #pragma unroll
  for (int kc = 0; kc < 3; ++kc) {
    const int ka = kc * 32 + quad * 8;
    const short8 A0h = (ka < 80) ? *(const short8*)(XAh + nn * XAs + ka) : *(const short8*)ZS;
    const short8 A0l = (ka < 80) ? *(const short8*)(XAl + nn * XAs + ka) : *(const short8*)ZS;
    const short8 A1h = (ka < 80) ? *(const short8*)(XAh + (16 + nn) * XAs + ka) : *(const short8*)ZS;
    const short8 A1l = (ka < 80) ? *(const short8*)(XAl + (16 + nn) * XAs + ka) : *(const short8*)ZS;
    const unsigned short* pf = g_Wf + (((ch * 3 + kc) * 2 + cl) * 2) * 512 + lane * 8;
    const short8 Bh = *(const short8*)pf, Bl = *(const short8*)(pf + 512);
    TERM3(C[0], A0h, A0l, Bh, Bl);
    TERM3(C[1], A1h, A1l, Bh, Bl);
  }
  #pragma unroll
  for (int mi = 0; mi < 2; ++mi)
    #pragma unroll
    for (int r = 0; r < 4; ++r) {
      const float v = fmaxf(C[mi][r] + g_W[B1O + col1], 0.f);
      unsigned short hu, lu; split2(v, hu, lu);
      XHh[(mi * 16 + quad * 4 + r) * XHs + col1] = hu;
      XHl[(mi * 16 + quad * 4 + r) * XHs + col1] = lu;
    }
  __syncthreads();

  // Phase 2: h1(K64) @ W2 -> h2
  C[0] = (f32x4){0.f,0.f,0.f,0.f}; C[1] = C[0];
  #pragma unroll
  for (int kc = 0; kc < 2; ++kc) {
    const int ka = kc * 32 + quad * 8;
    const short8 A0h = *(const short8*)(XHh + nn * XHs + ka);
    const short8 A0l = *(const short8*)(XHl + nn * XHs + ka);
    const short8 A1h = *(const short8*)(XHh + (16 + nn) * XHs + ka);
    const short8 A1l = *(const short8*)(XHl + (16 + nn) * XHs + ka);
    const unsigned short* pf = g_Wf + (F2F + ((ch * 2 + kc) * 2 + cl) * 2) * 512 + lane * 8;
    const short8 Bh = *(const short8*)pf, Bl = *(const short8*)(pf + 512);
    TERM3(C[0], A0h, A0l, Bh, Bl);
    TERM3(C[1], A1h, A1l, Bh, Bl);
  }
  __syncthreads();   // XA rewrite below
  #pragma unroll
  for (int mi = 0; mi < 2; ++mi)
    #pragma unroll
    for (int r = 0; r < 4; ++r) {
      const float v = fmaxf(C[mi][r] + g_W[B2O + col1], 0.f);
      unsigned short hu, lu; split2(v, hu, lu);
      XAh[(mi * 16 + quad * 4 + r) * XAs + col1] = hu;
      XAl[(mi * 16 + quad * 4 + r) * XAs + col1] = lu;
    }
  __syncthreads();

  // Phase 3: h2(K64) @ W3 -> h3 (128 cols)
  #pragma unroll
  for (int i = 0; i < 4; ++i) C[i] = (f32x4){0.f,0.f,0.f,0.f};
  #pragma unroll
  for (int kc = 0; kc < 2; ++kc) {
    const int ka = kc * 32 + quad * 8;
    const short8 A0h = *(const short8*)(XAh + nn * XAs + ka);
    const short8 A0l = *(const short8*)(XAl + nn * XAs + ka);
    const short8 A1h = *(const short8*)(XAh + (16 + nn) * XAs + ka);
    const short8 A1l = *(const short8*)(XAl + (16 + nn) * XAs + ka);
    #pragma unroll
    for (int c2 = 0; c2 < 2; ++c2) {
      const unsigned short* pf = g_Wf + (F3F + ((ch * 2 + kc) * 4 + cl * 2 + c2) * 2) * 512 + lane * 8;
      const short8 Bh = *(const short8*)pf, Bl = *(const short8*)(pf + 512);
      TERM3(C[0 + c2], A0h, A0l, Bh, Bl);
      TERM3(C[2 + c2], A1h, A1l, Bh, Bl);
    }
  }
  __syncthreads();   // XH rewrite below (rxyz cols preserved)
  #pragma unroll
  for (int c2 = 0; c2 < 2; ++c2) {
    const int col = w * 32 + c2 * 16 + nn;
    #pragma unroll
    for (int mi = 0; mi < 2; ++mi)
      #pragma unroll
      for (int r = 0; r < 4; ++r) {
        const float v = fmaxf(C[mi * 2 + c2][r] + g_W[B3O + col], 0.f);
        unsigned short hu, lu; split2(v, hu, lu);
        XHh[(mi * 16 + quad * 4 + r) * XHs + col] = hu;
        XHl[(mi * 16 + quad * 4 + r) * XHs + col] = lu;
      }
  }
  __syncthreads();

  // Phase 5: [h3|xyz](K160) @ A -> ebias -> g_fps
  #pragma unroll
  for (int i = 0; i < 4; ++i) C[i] = (f32x4){0.f,0.f,0.f,0.f};
  #pragma unroll
  for (int kc = 0; kc < 5; ++kc) {
    const int ka = kc * 32 + quad * 8;
    const short8 A0h = (ka < 144) ? *(const short8*)(XHh + nn * XHs + ka) : *(const short8*)ZS;
    const short8 A0l = (ka < 144) ? *(const short8*)(XHl + nn * XHs + ka) : *(const short8*)ZS;
    const short8 A1h = (ka < 144) ? *(const short8*)(XHh + (16 + nn) * XHs + ka) : *(const short8*)ZS;
    const short8 A1l = (ka < 144) ? *(const short8*)(XHl + (16 + nn) * XHs + ka) : *(const short8*)ZS;
    #pragma unroll
    for (int c2 = 0; c2 < 2; ++c2) {
      const unsigned short* pf = g_Wf + (F5F + ((ch * 5 + kc) * 4 + cl * 2 + c2) * 2) * 512 + lane * 8;
      const short8 Bh = *(const short8*)pf, Bl = *(const short8*)(pf + 512);
      TERM3(C[0 + c2], A0h, A0l, Bh, Bl);
      TERM3(C[2 + c2], A1h, A1l, Bh, Bl);
    }
  }
  #pragma unroll
  for (int c2 = 0; c2 < 2; ++c2) {
    const int col = w * 32 + c2 * 16 + nn;
    #pragma unroll
    for (int mi = 0; mi < 2; ++mi)
      #pragma unroll
      for (int r = 0; r < 4; ++r)
        g_fps[(long)(g0 + mi * 16 + quad * 4 + r) * 132 + col] = C[mi * 2 + c2][r];
  }
}

// Epilogue: g_tmp[b][p][128] -> out1[b][c][p]
__global__ __launch_bounds__(256) void transpose_out(float* __restrict__ out)
{
  __shared__ float T[64 * 129];
  const int t = threadIdx.x;
  const int b = blockIdx.x >> 4, p0 = (blockIdx.x & 15) << 6;
  const int c = t & 127, ph = t >> 7;
  #pragma unroll
  for (int pp = 0; pp < 32; ++pp) {
    const int pi = ph * 32 + pp;
    T[pi * 129 + c] = g_tmp[(((long)b << 10) + p0 + pi) * 128 + c];
  }
  __syncthreads();
  const int pn = t & 63, cg = t >> 6;
  #pragma unroll
  for (int k = 0; k < 32; ++k) {
    const int cc = cg * 32 + k;
    out[Bn * 3 * Pn + ((b << 7) + cc) * Pn + p0 + pn] = T[pn * 129 + cc];
  }
}

// ---- fused kernel: waves = 4 col-quarters x all 32 rows. Each weight
// fragment is read exactly ONCE per block (halves g_Wf L2 traffic), and the
// softmax-over-neighbors reduction is fully wave-local (shfl over quads).
#define OXA 0            // 32*88*2  = 5632
#define OXH 5632         // 32*152*2 = 9728 -> 15360
#define OFS 15360        // 128 f32  = 512  -> 15872
#define OZS 15872        // 16 B zero stub  -> 15888
#define LDSB 15888

__global__ __launch_bounds__(256, 8) void fused_kernel(
    const int* __restrict__ group_idx)
{
  __shared__ __align__(16) unsigned char LB[LDSB];
  unsigned short* XAh = (unsigned short*)(LB + OXA);
  unsigned short* XHh = (unsigned short*)(LB + OXH);
  float*          FS  = (float*)(LB + OFS);
  unsigned short* ZS  = (unsigned short*)(LB + OZS);

  const int t = threadIdx.x, lane = t & 63, w = t >> 6;
  const int quad = lane >> 4, nn = lane & 15;
  const int ch = w >> 1, cl = w & 1;
  // XCD swizzle: 16384 blocks -> each XCD gets 2 contiguous b-slabs (L2-fit)
  const int g = ((blockIdx.x & 7) << 11) | (blockIdx.x >> 3);
  const int b = g >> 10;

  // ---- S0: stage ebias; zero stub ----
  if (t < 128) FS[t] = g_fps[(long)g * 132 + t];
  if (t < 4) ((float*)ZS)[t] = 0.f;

  // ---- S1: gather group rows -> XAh; rxyz; pads ----
  {
    const int s0 = t >> 3, cg = t & 7;
    const int gi = group_idx[g * Sn + s0];
    const float* prow = g_pts + (((long)b << 12) + gi) * 68;
    const int c0 = cg * 8;
    const float4 va = *(const float4*)(prow + c0);
    const float4 vb = *(const float4*)(prow + c0 + 4);
    short8 hv;
    hv[0] = (short)bfh(va.x); hv[1] = (short)bfh(va.y);
    hv[2] = (short)bfh(va.z); hv[3] = (short)bfh(va.w);
    hv[4] = (short)bfh(vb.x); hv[5] = (short)bfh(vb.y);
    hv[6] = (short)bfh(vb.z); hv[7] = (short)bfh(vb.w);
    *(short8*)(XAh + s0 * XAs + c0) = hv;
    if (cg == 0) {
      #pragma unroll
      for (int d = 0; d < 3; ++d) {
        const float r = prow[64 + d] - g_fps[(long)g * 132 + 128 + d];
        const unsigned short hu = bfh(r);
        XAh[s0 * XAs + 64 + d] = hu;
        XHh[s0 * XHs + 128 + d] = hu;
      }
    } else if (cg == 1) {
      #pragma unroll
      for (int j = 0; j < 13; ++j) XAh[s0 * XAs + 67 + j] = 0;
    } else if (cg == 2) {
      #pragma unroll
      for (int j = 0; j < 13; ++j) XHh[s0 * XHs + 131 + j] = 0;
    }
  }
  __syncthreads();

  f32x4 C[4];
  const int col1 = w * 16 + nn;

  // ===== Phase 1: X(K96) @ W1f -> h1 (XHh cols 0..63) =====
  C[0] = (f32x4){0.f,0.f,0.f,0.f}; C[1] = C[0];
  #pragma unroll
  for (int kc = 0; kc < 3; ++kc) {
    const int ka = kc * 32 + quad * 8;
    const short8 A0 = (ka < 80) ? *(const short8*)(XAh + nn * XAs + ka) : *(const short8*)ZS;
    const short8 A1 = (ka < 80) ? *(const short8*)(XAh + (16 + nn) * XAs + ka) : *(const short8*)ZS;
    const unsigned short* pf = g_Wf + (((ch * 3 + kc) * 2 + cl) * 2) * 512 + lane * 8;
    const short8 Bh = *(const short8*)pf, Bl = *(const short8*)(pf + 512);
    C[0] = MFMA_BF16(A0, Bh, C[0], 0, 0, 0);
    C[0] = MFMA_BF16(A0, Bl, C[0], 0, 0, 0);
    C[1] = MFMA_BF16(A1, Bh, C[1], 0, 0, 0);
    C[1] = MFMA_BF16(A1, Bl, C[1], 0, 0, 0);
  }
  #pragma unroll
  for (int mi = 0; mi < 2; ++mi)
    #pragma unroll
    for (int r = 0; r < 4; ++r)
      XHh[(mi * 16 + quad * 4 + r) * XHs + col1] =
          bfh(fmaxf(C[mi][r] + g_W[B1O + col1], 0.f));
  __syncthreads();

  // ===== Phase 2: h1(K64, XHh) @ W2f -> h2 (XAh cols 0..63) =====
  C[0] = (f32x4){0.f,0.f,0.f,0.f}; C[1] = C[0];
  #pragma unroll
  for (int kc = 0; kc < 2; ++kc) {
    const int ka = kc * 32 + quad * 8;
    const short8 A0 = *(const short8*)(XHh + nn * XHs + ka);
    const short8 A1 = *(const short8*)(XHh + (16 + nn) * XHs + ka);
    const unsigned short* pf = g_Wf + (F2F + ((ch * 2 + kc) * 2 + cl) * 2) * 512 + lane * 8;
    const short8 Bh = *(const short8*)pf, Bl = *(const short8*)(pf + 512);
    C[0] = MFMA_BF16(A0, Bh, C[0], 0, 0, 0);
    C[0] = MFMA_BF16(A0, Bl, C[0], 0, 0, 0);
    C[1] = MFMA_BF16(A1, Bh, C[1], 0, 0, 0);
    C[1] = MFMA_BF16(A1, Bl, C[1], 0, 0, 0);
  }
  #pragma unroll
  for (int mi = 0; mi < 2; ++mi)
    #pragma unroll
    for (int r = 0; r < 4; ++r)
      XAh[(mi * 16 + quad * 4 + r) * XAs + col1] =
          bfh(fmaxf(C[mi][r] + g_W[B2O + col1], 0.f));
  __syncthreads();

  // ===== Phase 3: h2(K64, XAh) @ W3f -> h3 (XHh cols 0..127) =====
  #pragma unroll
  for (int i = 0; i < 4; ++i) C[i] = (f32x4){0.f,0.f,0.f,0.f};
  #pragma unroll
  for (int kc = 0; kc < 2; ++kc) {
    const int ka = kc * 32 + quad * 8;
    const short8 A0 = *(const short8*)(XAh + nn * XAs + ka);
    const short8 A1 = *(const short8*)(XAh + (16 + nn) * XAs + ka);
    #pragma unroll
    for (int c2 = 0; c2 < 2; ++c2) {
      const unsigned short* pf = g_Wf + (F3F + ((ch * 2 + kc) * 4 + cl * 2 + c2) * 2) * 512 + lane * 8;
      const short8 Bh = *(const short8*)pf, Bl = *(const short8*)(pf + 512);
      C[0 + c2] = MFMA_BF16(A0, Bh, C[0 + c2], 0, 0, 0);
      C[0 + c2] = MFMA_BF16(A0, Bl, C[0 + c2], 0, 0, 0);
      C[2 + c2] = MFMA_BF16(A1, Bh, C[2 + c2], 0, 0, 0);
      C[2 + c2] = MFMA_BF16(A1, Bl, C[2 + c2], 0, 0, 0);
    }
  }
  #pragma unroll
  for (int c2 = 0; c2 < 2; ++c2) {
    const int col = w * 32 + c2 * 16 + nn;
    #pragma unroll
    for (int mi = 0; mi < 2; ++mi)
      #pragma unroll
      for (int r = 0; r < 4; ++r)
        XHh[(mi * 16 + quad * 4 + r) * XHs + col] =
            bfh(fmaxf(C[mi * 2 + c2][r] + g_W[B3O + col], 0.f));
  }
  __syncthreads();

  // ===== Phase 5: [h3|rxyz](K160, XHh) @ Af -> scores (registers) =====
  #pragma unroll
  for (int i = 0; i < 4; ++i) C[i] = (f32x4){0.f,0.f,0.f,0.f};
  #pragma unroll
  for (int kc = 0; kc < 5; ++kc) {
    const int ka = kc * 32 + quad * 8;
    const short8 A0 = (ka < 144) ? *(const short8*)(XHh + nn * XHs + ka) : *(const short8*)ZS;
    const short8 A1 = (ka < 144) ? *(const short8*)(XHh + (16 + nn) * XHs + ka) : *(const short8*)ZS;
    #pragma unroll
    for (int c2 = 0; c2 < 2; ++c2) {
      const unsigned short* pf = g_Wf + (F5F + ((ch * 5 + kc) * 4 + cl * 2 + c2) * 2) * 512 + lane * 8;
      const short8 Bh = *(const short8*)pf, Bl = *(const short8*)(pf + 512);
      C[0 + c2] = MFMA_BF16(A0, Bh, C[0 + c2], 0, 0, 0);
      C[0 + c2] = MFMA_BF16(A0, Bl, C[0 + c2], 0, 0, 0);
      C[2 + c2] = MFMA_BF16(A1, Bh, C[2 + c2], 0, 0, 0);
      C[2 + c2] = MFMA_BF16(A1, Bl, C[2 + c2], 0, 0, 0);
    }
  }

  // ---- wave-local softmax + pool: each wave owns 32 cols x all 32 rows ----
  #pragma unroll
  for (int c2 = 0; c2 < 2; ++c2) {
    const int col = w * 32 + c2 * 16 + nn;
    const float eb = FS[col];
    float m_ = -3.4e38f;
    #pragma unroll
    for (int mi = 0; mi < 2; ++mi)
      #pragma unroll
      for (int r = 0; r < 4; ++r) {
        float e = eb - C[mi * 2 + c2][r];
        e = (e > 0.f) ? e : ALPHAn * e;
        C[mi * 2 + c2][r] = e;
        m_ = fmaxf(m_, e);
      }
    m_ = fmaxf(m_, __shfl_xor(m_, 16));
    m_ = fmaxf(m_, __shfl_xor(m_, 32));
    float den = 0.f, pool = 0.f;
    #pragma unroll
    for (int mi = 0; mi < 2; ++mi)
      #pragma unroll
      for (int r = 0; r < 4; ++r) {
        const float wgt = __expf(C[mi * 2 + c2][r] - m_);
        den += wgt;
        pool = fmaf(wgt, bf2f(XHh[(mi * 16 + quad * 4 + r) * XHs + col]), pool);
      }
    den  += __shfl_xor(den, 16);  den  += __shfl_xor(den, 32);
    pool += __shfl_xor(pool, 16); pool += __shfl_xor(pool, 32);
    if (quad == 0) g_tmp[(long)g * 128 + col] = pool / den;
  }
}

extern "C" void kernel_launch(void* const* d_in, const int* in_sizes, int n_in,
                              void* d_out, int out_size, void* d_ws, size_t ws_size,
                              hipStream_t stream) {
  const float* xyz       = (const float*)d_in[0];
  const float* points    = (const float*)d_in[1];
  const int*   fps_idx   = (const int*)d_in[2];
  const int*   group_idx = (const int*)d_in[3];

  const int prep_blocks = 1024 + (WSF + WFU + 255) / 256;
  prep_kernel<<<prep_blocks, 256, 0, stream>>>(
      xyz, points,
      (const float*)d_in[4],  (const float*)d_in[5],
      (const float*)d_in[6],  (const float*)d_in[7],
      (const float*)d_in[8],  (const float*)d_in[9],
      (const float*)d_in[10], (const float*)d_in[11],
      (const float*)d_in[12], (const float*)d_in[13],
      (const float*)d_in[14], (const float*)d_in[15],
      (const float*)d_in[16], (const float*)d_in[17],
      (const float*)d_in[18], (const float*)d_in[19],
      (const float*)d_in[20], (const float*)d_in[21],
      (const float*)d_in[22]);

  fps_kernel<<<512, 256, 0, stream>>>(fps_idx, (float*)d_out);

  fused_kernel<<<Bn * Pn, 256, 0, stream>>>(group_idx);

  transpose_out<<<Bn * 16, 256, 0, stream>>>((float*)d_out);
}